// Round 9
// baseline (219.264 us; speedup 1.0000x reference)
//
#include <hip/hip_runtime.h>

// ---------------------------------------------------------------------------
// SimpleVisionAttention on MI355X (gfx950)
// S=2048, DIM=1280 (16 heads x 80), fp32 in/out, f16 MFMA internally.
//
// Pipeline:
//   K1  fused cast fp32 -> f16   (hs, w_qkv, w_proj)
//   K2  QKV GEMM  (M=2048,N=3840,K=1280)  async global_load_lds staging
//   K3  fused RoPE + repack Qh/Kh [h][s][96] + V transpose -> Vt[h][d][s]
//   K4  flash attention, transposed dataflow (S^T->P^T in regs), fixed-max
//       base-2 softmax, KV-split x4, fragment-major V tiles in LDS.
//   K4b combine 4 partials (weighted by per-split l)
//   K5  proj GEMM, split-K x2, fp32 atomic epilogue -> d_out
// ---------------------------------------------------------------------------

#define SEQLEN   2048
#define DIMM     1280
#define NHEADS   16
#define HD       80
#define HDP      96          // padded head dim for Q/K (3 x 32 mfma K-steps)
#define QKV_N    3840
#define NSPLIT   4
#define KVSPAN   (SEQLEN / NSPLIT)
// SCALE * log2(e) folded into Q at rope time; softmax done in base-2.
#define QSCALE_LOG2E 0.16130083587064776f   // 80^-0.5 * 1.4426950408889634

#define KSTRIDE  104         // K-tile LDS row stride (halves): uniform banks

// device base-2 exp: v_exp_f32 (NOT __exp2f — collides with glibc math.h)
#define EXP2F(x) __builtin_amdgcn_exp2f(x)

// async global->LDS, 16B per lane; LDS dest must be waveBase + lane*16
#define GLD16(gptr, lptr)                                                      \
    __builtin_amdgcn_global_load_lds(                                          \
        (const __attribute__((address_space(1))) void*)(gptr),                 \
        (__attribute__((address_space(3))) void*)(lptr), 16, 0, 0)

typedef float f32x4 __attribute__((ext_vector_type(4)));
typedef _Float16 half8 __attribute__((ext_vector_type(8)));
typedef _Float16 half4 __attribute__((ext_vector_type(4)));

static __device__ __forceinline__ f32x4 mfma_16x16x32(half8 a, half8 b, f32x4 c) {
    return __builtin_amdgcn_mfma_f32_16x16x32_f16(a, b, c, 0, 0, 0);
}
// NOTE: legacy K=16 shape is spelled WITHOUT the underscore: ...16x16x16f16
static __device__ __forceinline__ f32x4 mfma_16x16x16(half4 a, half4 b, f32x4 c) {
    return __builtin_amdgcn_mfma_f32_16x16x16f16(a, b, c, 0, 0, 0);
}
static __device__ __forceinline__ half4 lo4(half8 v) {
    return __builtin_shufflevector(v, v, 0, 1, 2, 3);
}
static __device__ __forceinline__ half4 hi4(half8 v) {
    return __builtin_shufflevector(v, v, 4, 5, 6, 7);
}

// ---------------------------------------------------------------------------
// One fused cast kernel for the three fp32->f16 conversions.
__global__ __launch_bounds__(256)
void cast_all(const float* __restrict__ hs, const float* __restrict__ wq,
              const float* __restrict__ wp, _Float16* __restrict__ dhs,
              _Float16* __restrict__ dwq, _Float16* __restrict__ dwp) {
    const int n1 = SEQLEN * DIMM / 4, n2 = QKV_N * DIMM / 4, n3 = DIMM * DIMM / 4;
    int i = blockIdx.x * 256 + threadIdx.x;
    const float4* src; half4* dst; int j;
    if (i < n1)           { src = (const float4*)hs; dst = (half4*)dhs; j = i; }
    else if (i < n1 + n2) { src = (const float4*)wq; dst = (half4*)dwq; j = i - n1; }
    else if (i < n1 + n2 + n3) { src = (const float4*)wp; dst = (half4*)dwp; j = i - n1 - n2; }
    else return;
    const float4 v = src[j];
    half4 h;
    h.x = (_Float16)v.x; h.y = (_Float16)v.y;
    h.z = (_Float16)v.z; h.w = (_Float16)v.w;
    dst[j] = h;
}

// ---------------------------------------------------------------------------
// C[m][n] = sum_k A[m][k] * B[n][k] + bias[n]
// A: M x K f16 row-major, B: N x K f16 row-major (i.e. B^T layout).
// 128x128 tile, BK=32, 4 waves 2x2, async 16B global_load_lds staging.
template<bool OUT_F16>
__global__ __launch_bounds__(256, 2)
void gemm_bt(const _Float16* __restrict__ A, const _Float16* __restrict__ B,
             const float* __restrict__ bias, void* __restrict__ Cout,
             int M, int N, int K) {
    __shared__ __align__(16) _Float16 As[128 * 32];
    __shared__ __align__(16) _Float16 Bs[128 * 32];
    const int tid  = threadIdx.x;
    const int lane = tid & 63;
    const int wave = tid >> 6;
    const int l15  = lane & 15;
    const int quad = lane >> 4;
    const int wm   = wave & 1;
    const int wn   = wave >> 1;
    const long bm = blockIdx.x, bn = blockIdx.y;

    const _Float16* Ag = A + bm * 128 * (long)K;
    const _Float16* Bg = B + bn * 128 * (long)K;

    const int srow = lane >> 2;            // 0..15 within chunk
    const int scol = (lane & 3) * 8;       // halves
    f32x4 acc[4][4] = {};

    for (int k0 = 0; k0 < K; k0 += 32) {
        __syncthreads();
#pragma unroll
        for (int cc = 0; cc < 2; cc++) {
            const int c = wave + cc * 4;
            const long row = 16 * c + srow;
            GLD16(Ag + row * K + k0 + scol, As + 512 * c + lane * 8);
            GLD16(Bg + row * K + k0 + scol, Bs + 512 * c + lane * 8);
        }
        __syncthreads();
        half8 af[4], bf[4];
#pragma unroll
        for (int t = 0; t < 4; t++) {
            af[t] = *(const half8*)&As[(wm * 64 + t * 16 + l15) * 32 + quad * 8];
            bf[t] = *(const half8*)&Bs[(wn * 64 + t * 16 + l15) * 32 + quad * 8];
        }
#pragma unroll
        for (int mt = 0; mt < 4; mt++)
#pragma unroll
            for (int nt = 0; nt < 4; nt++)
                acc[mt][nt] = mfma_16x16x32(af[mt], bf[nt], acc[mt][nt]);
    }

    float bv[4];
#pragma unroll
    for (int nt = 0; nt < 4; nt++)
        bv[nt] = bias[bn * 128 + wn * 64 + nt * 16 + l15];

#pragma unroll
    for (int mt = 0; mt < 4; mt++) {
#pragma unroll
        for (int r = 0; r < 4; r++) {
            const long row = bm * 128 + wm * 64 + mt * 16 + quad * 4 + r;
#pragma unroll
            for (int nt = 0; nt < 4; nt++) {
                const long col = bn * 128 + wn * 64 + nt * 16 + l15;
                const float v = acc[mt][nt][r] + bv[nt];
                if (OUT_F16) ((_Float16*)Cout)[row * (long)N + col] = (_Float16)v;
                else         ((float*)Cout)[row * (long)N + col] = v;
            }
        }
    }
}

// ---------------------------------------------------------------------------
// Split-K (x2) variant for the proj GEMM: fp32 atomic accumulate into zeroed
// C; bias contributed by split 0 only.
__global__ __launch_bounds__(256, 2)
void gemm_bt_sk(const _Float16* __restrict__ A, const _Float16* __restrict__ B,
                const float* __restrict__ bias, float* __restrict__ Cout,
                int M, int N, int K) {
    __shared__ __align__(16) _Float16 As[128 * 32];
    __shared__ __align__(16) _Float16 Bs[128 * 32];
    const int tid  = threadIdx.x;
    const int lane = tid & 63;
    const int wave = tid >> 6;
    const int l15  = lane & 15;
    const int quad = lane >> 4;
    const int wm   = wave & 1;
    const int wn   = wave >> 1;
    const long bm = blockIdx.x, bn = blockIdx.y;
    const int  z  = blockIdx.z;
    const int  kHalf = K / 2;

    const _Float16* Ag = A + bm * 128 * (long)K;
    const _Float16* Bg = B + bn * 128 * (long)K;

    const int srow = lane >> 2;
    const int scol = (lane & 3) * 8;
    f32x4 acc[4][4] = {};

    for (int k0 = z * kHalf; k0 < (z + 1) * kHalf; k0 += 32) {
        __syncthreads();
#pragma unroll
        for (int cc = 0; cc < 2; cc++) {
            const int c = wave + cc * 4;
            const long row = 16 * c + srow;
            GLD16(Ag + row * K + k0 + scol, As + 512 * c + lane * 8);
            GLD16(Bg + row * K + k0 + scol, Bs + 512 * c + lane * 8);
        }
        __syncthreads();
        half8 af[4], bf[4];
#pragma unroll
        for (int t = 0; t < 4; t++) {
            af[t] = *(const half8*)&As[(wm * 64 + t * 16 + l15) * 32 + quad * 8];
            bf[t] = *(const half8*)&Bs[(wn * 64 + t * 16 + l15) * 32 + quad * 8];
        }
#pragma unroll
        for (int mt = 0; mt < 4; mt++)
#pragma unroll
            for (int nt = 0; nt < 4; nt++)
                acc[mt][nt] = mfma_16x16x32(af[mt], bf[nt], acc[mt][nt]);
    }

    float bv[4];
#pragma unroll
    for (int nt = 0; nt < 4; nt++)
        bv[nt] = (z == 0) ? bias[bn * 128 + wn * 64 + nt * 16 + l15] : 0.f;

#pragma unroll
    for (int mt = 0; mt < 4; mt++) {
#pragma unroll
        for (int r = 0; r < 4; r++) {
            const long row = bm * 128 + wm * 64 + mt * 16 + quad * 4 + r;
#pragma unroll
            for (int nt = 0; nt < 4; nt++) {
                const long col = bn * 128 + wn * 64 + nt * 16 + l15;
                unsafeAtomicAdd(&Cout[row * (long)N + col], acc[mt][nt][r] + bv[nt]);
            }
        }
    }
}

// ---------------------------------------------------------------------------
// Fused: RoPE on q,k -> Qh/Kh [h][s][96] (Q pre-scaled by SCALE*log2e, pads
// zeroed) + V transposed via LDS -> Vt[h][d][s]. Block = (64 seqs, 1 head).
__global__ __launch_bounds__(256)
void rope_repack_t(const _Float16* __restrict__ qkv,
                   const float* __restrict__ cosb,
                   const float* __restrict__ sinb,
                   _Float16* __restrict__ Qh,
                   _Float16* __restrict__ Kh,
                   _Float16* __restrict__ Vt) {
    const int s0 = blockIdx.x * 64;
    const int h  = blockIdx.y;
    __shared__ __align__(16) _Float16 Ts[64 * 88];
    const int tid = threadIdx.x;

    // stage V rows into LDS (transposed write later)
    for (int i = tid; i < 640; i += 256) {          // 64 rows x 10 chunks
        const int r = i / 10, c = (i - r * 10) * 8;
        *(half8*)&Ts[r * 88 + c] =
            *(const half8*)&qkv[(long)(s0 + r) * QKV_N + 2 * DIMM + h * HD + c];
    }

    // q,k rope: 64 rows x 5 chunks of 8 (d in [0,40))
    for (int i = tid; i < 320; i += 256) {
        const int r = i / 5, d = (i - r * 5) * 8;
        const _Float16* row = qkv + (long)(s0 + r) * QKV_N + h * HD;
        const half8 q0 = *(const half8*)&row[d];
        const half8 q1 = *(const half8*)&row[d + 40];
        const half8 k0 = *(const half8*)&row[DIMM + d];
        const half8 k1 = *(const half8*)&row[DIMM + d + 40];
        const float4 cA = *(const float4*)&cosb[(s0 + r) * HD + d];
        const float4 cB = *(const float4*)&cosb[(s0 + r) * HD + d + 4];
        const float4 sA = *(const float4*)&sinb[(s0 + r) * HD + d];
        const float4 sB = *(const float4*)&sinb[(s0 + r) * HD + d + 4];
        half8 qo0, qo1, ko0, ko1;
#pragma unroll
        for (int j = 0; j < 8; j++) {
            const float cj = (j < 4) ? cA[j] : cB[j - 4];
            const float sj = (j < 4) ? sA[j] : sB[j - 4];
            qo0[j] = (_Float16)(((float)q0[j] * cj - (float)q1[j] * sj) * QSCALE_LOG2E);
            qo1[j] = (_Float16)(((float)q1[j] * cj + (float)q0[j] * sj) * QSCALE_LOG2E);
            ko0[j] = (_Float16)((float)k0[j] * cj - (float)k1[j] * sj);
            ko1[j] = (_Float16)((float)k1[j] * cj + (float)k0[j] * sj);
        }
        const long o = ((long)h * SEQLEN + s0 + r) * HDP;
        *(half8*)&Qh[o + d]      = qo0;
        *(half8*)&Qh[o + d + 40] = qo1;
        *(half8*)&Kh[o + d]      = ko0;
        *(half8*)&Kh[o + d + 40] = ko1;
    }
    // zero pads d in [80,96)
    for (int i = tid; i < 128; i += 256) {
        const int r = i >> 1, off = HD + (i & 1) * 8;
        const long o = ((long)h * SEQLEN + s0 + r) * HDP + off;
        *(half8*)&Qh[o] = (half8)(_Float16)0.f;
        *(half8*)&Kh[o] = (half8)(_Float16)0.f;
    }
    __syncthreads();
    // transposed V out: 80 d-rows x 8 s-chunks
    for (int i = tid; i < 640; i += 256) {
        const int d = i >> 3, sc = (i & 7) * 8;
        half8 v;
#pragma unroll
        for (int j = 0; j < 8; j++) v[j] = Ts[(sc + j) * 88 + d];
        *(half8*)&Vt[((long)h * HD + d) * SEQLEN + s0 + sc] = v;
    }
}

// ---------------------------------------------------------------------------
// Flash attention, transposed dataflow, fixed-max base-2 softmax, KV-split x4.
// 512-thread blocks: 8 waves x 16 q-rows = 128 q-rows/block; 64-key tiles.
//
// S^T = mfma_16x16x32(K_frag, Q_frag): lane holds query=l15, keys=quad*4+r.
// P^T = exp2(S^T) feeds PV directly as the 16x16x16 B-operand.
// V staged FRAGMENT-MAJOR: VF[nt][lane][16] — lane's full A-fragment for all
// 4 ct tiles is 16 contiguous halves -> 2 lane-contiguous half8 reads per nt
// (uniform banks; replaces 20 conflicted half4 reads of round 8).
// LDS 23.0 KB -> 4 blocks/CU, grid 1024 exactly resident.
__global__ __launch_bounds__(512, 8)
void attn_kernel(const _Float16* __restrict__ Qh, const _Float16* __restrict__ Kh,
                 const _Float16* __restrict__ Vt,
                 _Float16* __restrict__ Ohat0, _Float16* __restrict__ Ohat1,
                 float* __restrict__ Lpart) {
    const int s0 = blockIdx.x * 128;
    const int h  = blockIdx.y;
    const int z  = blockIdx.z;
    __shared__ __align__(16) _Float16 Ks[64 * KSTRIDE];   // 13.0 KB
    __shared__ __align__(16) _Float16 VF[5 * 64 * 16];    // 10.0 KB

    const int tid  = threadIdx.x;
    const int lane = tid & 63;
    const int wave = tid >> 6;
    const int l15  = lane & 15;
    const int quad = lane >> 4;

    const _Float16* Qg = Qh + ((long)h * SEQLEN + s0 + wave * 16 + l15) * HDP;
    half8 qf[3];
#pragma unroll
    for (int kk = 0; kk < 3; kk++)
        qf[kk] = *(const half8*)&Qg[kk * 32 + quad * 8];

    f32x4 oaccT[5] = {};
    float l_acc = 0.f;

    for (int t0 = z * KVSPAN; t0 < (z + 1) * KVSPAN; t0 += 64) {
        __syncthreads();
        const _Float16* Kg = Kh + ((long)h * SEQLEN + t0) * HDP;
        for (int i = tid; i < 768; i += 512) {       // 64 rows x 12 chunks
            const int r = i / 12, c = (i - r * 12) * 8;
            *(half8*)&Ks[r * KSTRIDE + c] = *(const half8*)&Kg[(long)r * HDP + c];
        }
        const _Float16* Vtg = Vt + (long)h * HD * SEQLEN + t0;
        for (int i = tid; i < 640; i += 512) {       // 80 d-rows x 8 chunks
            const int d = i >> 3, c = (i & 7) * 8;
            const half8 v = *(const half8*)&Vtg[(long)d * SEQLEN + c];
            const int nt = d >> 4, ld = d & 15;
            const int ct = c >> 4, qb = (c & 15) >> 2;   // qb in {0, 2}
            *(half4*)&VF[(nt * 64 + qb * 16 + ld) * 16 + ct * 4]       = lo4(v);
            *(half4*)&VF[(nt * 64 + (qb + 1) * 16 + ld) * 16 + ct * 4] = hi4(v);
        }
        __syncthreads();

        // S^T: 4 col-tiles of 16 keys each (operands swapped: A=K, B=Q)
        f32x4 sa[4] = {};
#pragma unroll
        for (int kk = 0; kk < 3; kk++)
#pragma unroll
            for (int ct = 0; ct < 4; ct++) {
                half8 kf = *(const half8*)&Ks[(ct * 16 + l15) * KSTRIDE + kk * 32 + quad * 8];
                sa[ct] = mfma_16x16x32(kf, qf[kk], sa[ct]);
            }

        // P^T = exp2(S^T) straight into 16x16x16 B-operand registers
        half4 pb[4];
#pragma unroll
        for (int ct = 0; ct < 4; ct++)
#pragma unroll
            for (int r = 0; r < 4; r++) {
                const float p = EXP2F(sa[ct][r]);
                l_acc += p;
                pb[ct][r] = (_Float16)p;
            }

        // O^T += V^T * P^T : 2 lane-contiguous half8 reads per nt
#pragma unroll
        for (int nt = 0; nt < 5; nt++) {
            const half8 va = *(const half8*)&VF[(nt * 64 + lane) * 16];
            const half8 vb = *(const half8*)&VF[(nt * 64 + lane) * 16 + 8];
            oaccT[nt] = mfma_16x16x16(lo4(va), pb[0], oaccT[nt]);
            oaccT[nt] = mfma_16x16x16(hi4(va), pb[1], oaccT[nt]);
            oaccT[nt] = mfma_16x16x16(lo4(vb), pb[2], oaccT[nt]);
            oaccT[nt] = mfma_16x16x16(hi4(vb), pb[3], oaccT[nt]);
        }
    }

    // l: sum the 4 quads holding this query's key-chunks
    l_acc += __shfl_xor(l_acc, 16);
    l_acc += __shfl_xor(l_acc, 32);
    const float inv = 1.0f / l_acc;

    // partials: z 0,1 -> Ohat0 region, z 2,3 -> Ohat1 region
    _Float16* Oz = (z < 2) ? Ohat0 : Ohat1;
    const long obase = ((long)(z & 1) * NHEADS + h) * SEQLEN;
    const long lbase = ((long)z * NHEADS + h) * SEQLEN;
    const long row = s0 + wave * 16 + l15;           // this lane's query
#pragma unroll
    for (int nt = 0; nt < 5; nt++) {
        half4 o;
#pragma unroll
        for (int r = 0; r < 4; r++) o[r] = (_Float16)(oaccT[nt][r] * inv);
        *(half4*)&Oz[(obase + row) * HD + nt * 16 + quad * 4] = o;
    }
    if (quad == 0)
        Lpart[lbase + row] = l_acc;
}

// ---------------------------------------------------------------------------
// out = sum_z Ohat_z * l_z / sum_z l_z  -> attnb f16 [s][h*80+d]
__global__ __launch_bounds__(256)
void attn_combine(const _Float16* __restrict__ Ohat0,
                  const _Float16* __restrict__ Ohat1,
                  const float* __restrict__ Lp,
                  _Float16* __restrict__ attnb) {
    const int i = blockIdx.x * 256 + threadIdx.x;
    if (i >= SEQLEN * DIMM / 4) return;
    const int flat = i * 4;
    const int s = flat / DIMM;
    const int rem = flat - s * DIMM;
    const int h = rem / HD;
    const int d = rem - h * HD;
    float l[NSPLIT], lsum = 0.f;
#pragma unroll
    for (int zi = 0; zi < NSPLIT; zi++) {
        l[zi] = Lp[((long)zi * NHEADS + h) * SEQLEN + s];
        lsum += l[zi];
    }
    const float invl = 1.0f / lsum;
    float acc[4] = {0.f, 0.f, 0.f, 0.f};
#pragma unroll
    for (int zi = 0; zi < NSPLIT; zi++) {
        const _Float16* Oz = (zi < 2) ? Ohat0 : Ohat1;
        const long obase = ((long)(zi & 1) * NHEADS + h) * SEQLEN;
        const half4 o = *(const half4*)&Oz[(obase + s) * HD + d];
        const float w = l[zi] * invl;
#pragma unroll
        for (int j = 0; j < 4; j++) acc[j] += (float)o[j] * w;
    }
    half4 o;
#pragma unroll
    for (int j = 0; j < 4; j++) o[j] = (_Float16)acc[j];
    *(half4*)&attnb[(long)s * DIMM + rem] = o;
}

// ---------------------------------------------------------------------------
extern "C" void kernel_launch(void* const* d_in, const int* in_sizes, int n_in,
                              void* d_out, int out_size, void* d_ws, size_t ws_size,
                              hipStream_t stream) {
    const float* hs     = (const float*)d_in[0];
    // d_in[1] = cu_seqlens [0, 2048] — reference does no masking; unused.
    const float* cosb   = (const float*)d_in[2];
    const float* sinb   = (const float*)d_in[3];
    const float* w_qkv  = (const float*)d_in[4];
    const float* b_qkv  = (const float*)d_in[5];
    const float* w_proj = (const float*)d_in[6];
    const float* b_proj = (const float*)d_in[7];
    float* out = (float*)d_out;

    _Float16* hsb    = (_Float16*)d_ws;                       // 2048*1280
    _Float16* wqkvb  = hsb    + (long)SEQLEN * DIMM;          // 3840*1280
    _Float16* wprojb = wqkvb  + (long)QKV_N * DIMM;           // 1280*1280
    _Float16* qkv    = wprojb + (long)DIMM * DIMM;            // 2048*3840
    _Float16* Qh     = qkv    + (long)SEQLEN * QKV_N;         // 16*2048*96
    _Float16* Kh     = Qh     + (long)NHEADS * SEQLEN * HDP;
    _Float16* Vtb    = Kh     + (long)NHEADS * SEQLEN * HDP;  // 16*80*2048
    _Float16* attnb  = Vtb    + (long)NHEADS * HD * SEQLEN;   // 2048*1280

    // attention partials alias DEAD regions during attention:
    //   Ohat0 (z=0,1): hsb+wqkvb region (15.07 MB) — dead after QKV GEMM.
    //   Ohat1 (z=2,3): qkv region (15.73 MB) — dead after rope_repack_t.
    _Float16* Ohat0  = (_Float16*)d_ws;
    float*    LpartB = (float*)(Ohat0 + (long)2 * NHEADS * SEQLEN * HD);
    _Float16* Ohat1  = qkv;

    {
        const int ntot = (SEQLEN * DIMM + QKV_N * DIMM + DIMM * DIMM) / 4;
        cast_all<<<(ntot + 255) / 256, 256, 0, stream>>>(
            hs, w_qkv, w_proj, hsb, wqkvb, wprojb);
    }

    gemm_bt<true><<<dim3(SEQLEN / 128, QKV_N / 128), 256, 0, stream>>>(
        hsb, wqkvb, b_qkv, qkv, SEQLEN, QKV_N, DIMM);

    rope_repack_t<<<dim3(SEQLEN / 64, NHEADS), 256, 0, stream>>>(
        qkv, cosb, sinb, Qh, Kh, Vtb);

    attn_kernel<<<dim3(SEQLEN / 128, NHEADS, NSPLIT), 512, 0, stream>>>(
        Qh, Kh, Vtb, Ohat0, Ohat1, LpartB);

    attn_combine<<<(SEQLEN * DIMM / 4 + 255) / 256, 256, 0, stream>>>(
        Ohat0, Ohat1, LpartB, attnb);

    // zero d_out, then split-K proj GEMM accumulates into it
    hipMemsetAsync(out, 0, (size_t)SEQLEN * DIMM * sizeof(float), stream);
    gemm_bt_sk<<<dim3(SEQLEN / 128, DIMM / 128, 2), 256, 0, stream>>>(
        attnb, wprojb, b_proj, out, SEQLEN, DIMM, DIMM);
}

// Round 10
// 212.090 us; speedup vs baseline: 1.0338x; 1.0338x over previous
//
#include <hip/hip_runtime.h>

// ---------------------------------------------------------------------------
// SimpleVisionAttention on MI355X (gfx950)
// S=2048, DIM=1280 (16 heads x 80), fp32 in/out, f16 MFMA internally.
//
// Pipeline:
//   K1  fused cast fp32 -> f16   (hs, w_qkv, w_proj)
//   K2  QKV GEMM  (M=2048,N=3840,K=1280)  async global_load_lds staging
//   K3  fused RoPE + repack Qh/Kh [h][s][96] + V transpose -> Vt[h][d][s]
//   K4  flash attention, transposed dataflow (S^T->P^T in regs), fixed-max
//       base-2 softmax, KV-split x4, fragment-major V (stride 24: uniform banks)
//   K4b combine 4 partials (weighted by per-split l)
//   K5  proj GEMM + bias -> fp32 d_out   (plain; split-K regressed in R9)
// ---------------------------------------------------------------------------

#define SEQLEN   2048
#define DIMM     1280
#define NHEADS   16
#define HD       80
#define HDP      96          // padded head dim for Q/K (3 x 32 mfma K-steps)
#define QKV_N    3840
#define NSPLIT   4
#define KVSPAN   (SEQLEN / NSPLIT)
// SCALE * log2(e) folded into Q at rope time; softmax done in base-2.
#define QSCALE_LOG2E 0.16130083587064776f   // 80^-0.5 * 1.4426950408889634

#define KSTRIDE  104  // K-tile row stride (52 dw): read starts uniform, verified
#define VFSTRIDE 24   // VF row stride (12 dw): lane starts cover all 32 banks,
                      // 48B rows keep half8 reads 16B-aligned (16 dw was 2x-conflicted)

// device base-2 exp: v_exp_f32 (NOT __exp2f — collides with glibc math.h)
#define EXP2F(x) __builtin_amdgcn_exp2f(x)

// async global->LDS, 16B per lane; LDS dest must be waveBase + lane*16
#define GLD16(gptr, lptr)                                                      \
    __builtin_amdgcn_global_load_lds(                                          \
        (const __attribute__((address_space(1))) void*)(gptr),                 \
        (__attribute__((address_space(3))) void*)(lptr), 16, 0, 0)

typedef float f32x4 __attribute__((ext_vector_type(4)));
typedef _Float16 half8 __attribute__((ext_vector_type(8)));
typedef _Float16 half4 __attribute__((ext_vector_type(4)));

static __device__ __forceinline__ f32x4 mfma_16x16x32(half8 a, half8 b, f32x4 c) {
    return __builtin_amdgcn_mfma_f32_16x16x32_f16(a, b, c, 0, 0, 0);
}
// NOTE: legacy K=16 shape is spelled WITHOUT the underscore: ...16x16x16f16
static __device__ __forceinline__ f32x4 mfma_16x16x16(half4 a, half4 b, f32x4 c) {
    return __builtin_amdgcn_mfma_f32_16x16x16f16(a, b, c, 0, 0, 0);
}
static __device__ __forceinline__ half4 lo4(half8 v) {
    return __builtin_shufflevector(v, v, 0, 1, 2, 3);
}
static __device__ __forceinline__ half4 hi4(half8 v) {
    return __builtin_shufflevector(v, v, 4, 5, 6, 7);
}

// ---------------------------------------------------------------------------
// One fused cast kernel for the three fp32->f16 conversions.
__global__ __launch_bounds__(256)
void cast_all(const float* __restrict__ hs, const float* __restrict__ wq,
              const float* __restrict__ wp, _Float16* __restrict__ dhs,
              _Float16* __restrict__ dwq, _Float16* __restrict__ dwp) {
    const int n1 = SEQLEN * DIMM / 4, n2 = QKV_N * DIMM / 4, n3 = DIMM * DIMM / 4;
    int i = blockIdx.x * 256 + threadIdx.x;
    const float4* src; half4* dst; int j;
    if (i < n1)           { src = (const float4*)hs; dst = (half4*)dhs; j = i; }
    else if (i < n1 + n2) { src = (const float4*)wq; dst = (half4*)dwq; j = i - n1; }
    else if (i < n1 + n2 + n3) { src = (const float4*)wp; dst = (half4*)dwp; j = i - n1 - n2; }
    else return;
    const float4 v = src[j];
    half4 h;
    h.x = (_Float16)v.x; h.y = (_Float16)v.y;
    h.z = (_Float16)v.z; h.w = (_Float16)v.w;
    dst[j] = h;
}

// ---------------------------------------------------------------------------
// C[m][n] = sum_k A[m][k] * B[n][k] + bias[n]
// A: M x K f16 row-major, B: N x K f16 row-major (i.e. B^T layout).
// 128x128 tile, BK=32, 4 waves 2x2, async 16B global_load_lds staging.
template<bool OUT_F16>
__global__ __launch_bounds__(256, 2)
void gemm_bt(const _Float16* __restrict__ A, const _Float16* __restrict__ B,
             const float* __restrict__ bias, void* __restrict__ Cout,
             int M, int N, int K) {
    __shared__ __align__(16) _Float16 As[128 * 32];
    __shared__ __align__(16) _Float16 Bs[128 * 32];
    const int tid  = threadIdx.x;
    const int lane = tid & 63;
    const int wave = tid >> 6;
    const int l15  = lane & 15;
    const int quad = lane >> 4;
    const int wm   = wave & 1;
    const int wn   = wave >> 1;
    const long bm = blockIdx.x, bn = blockIdx.y;

    const _Float16* Ag = A + bm * 128 * (long)K;
    const _Float16* Bg = B + bn * 128 * (long)K;

    const int srow = lane >> 2;            // 0..15 within chunk
    const int scol = (lane & 3) * 8;       // halves
    f32x4 acc[4][4] = {};

    for (int k0 = 0; k0 < K; k0 += 32) {
        __syncthreads();
#pragma unroll
        for (int cc = 0; cc < 2; cc++) {
            const int c = wave + cc * 4;
            const long row = 16 * c + srow;
            GLD16(Ag + row * K + k0 + scol, As + 512 * c + lane * 8);
            GLD16(Bg + row * K + k0 + scol, Bs + 512 * c + lane * 8);
        }
        __syncthreads();
        half8 af[4], bf[4];
#pragma unroll
        for (int t = 0; t < 4; t++) {
            af[t] = *(const half8*)&As[(wm * 64 + t * 16 + l15) * 32 + quad * 8];
            bf[t] = *(const half8*)&Bs[(wn * 64 + t * 16 + l15) * 32 + quad * 8];
        }
#pragma unroll
        for (int mt = 0; mt < 4; mt++)
#pragma unroll
            for (int nt = 0; nt < 4; nt++)
                acc[mt][nt] = mfma_16x16x32(af[mt], bf[nt], acc[mt][nt]);
    }

    float bv[4];
#pragma unroll
    for (int nt = 0; nt < 4; nt++)
        bv[nt] = bias[bn * 128 + wn * 64 + nt * 16 + l15];

#pragma unroll
    for (int mt = 0; mt < 4; mt++) {
#pragma unroll
        for (int r = 0; r < 4; r++) {
            const long row = bm * 128 + wm * 64 + mt * 16 + quad * 4 + r;
#pragma unroll
            for (int nt = 0; nt < 4; nt++) {
                const long col = bn * 128 + wn * 64 + nt * 16 + l15;
                const float v = acc[mt][nt][r] + bv[nt];
                if (OUT_F16) ((_Float16*)Cout)[row * (long)N + col] = (_Float16)v;
                else         ((float*)Cout)[row * (long)N + col] = v;
            }
        }
    }
}

// ---------------------------------------------------------------------------
// Fused: RoPE on q,k -> Qh/Kh [h][s][96] (Q pre-scaled by SCALE*log2e, pads
// zeroed) + V transposed via LDS -> Vt[h][d][s]. Block = (64 seqs, 1 head).
__global__ __launch_bounds__(256)
void rope_repack_t(const _Float16* __restrict__ qkv,
                   const float* __restrict__ cosb,
                   const float* __restrict__ sinb,
                   _Float16* __restrict__ Qh,
                   _Float16* __restrict__ Kh,
                   _Float16* __restrict__ Vt) {
    const int s0 = blockIdx.x * 64;
    const int h  = blockIdx.y;
    __shared__ __align__(16) _Float16 Ts[64 * 88];
    const int tid = threadIdx.x;

    // stage V rows into LDS (transposed write later)
    for (int i = tid; i < 640; i += 256) {          // 64 rows x 10 chunks
        const int r = i / 10, c = (i - r * 10) * 8;
        *(half8*)&Ts[r * 88 + c] =
            *(const half8*)&qkv[(long)(s0 + r) * QKV_N + 2 * DIMM + h * HD + c];
    }

    // q,k rope: 64 rows x 5 chunks of 8 (d in [0,40))
    for (int i = tid; i < 320; i += 256) {
        const int r = i / 5, d = (i - r * 5) * 8;
        const _Float16* row = qkv + (long)(s0 + r) * QKV_N + h * HD;
        const half8 q0 = *(const half8*)&row[d];
        const half8 q1 = *(const half8*)&row[d + 40];
        const half8 k0 = *(const half8*)&row[DIMM + d];
        const half8 k1 = *(const half8*)&row[DIMM + d + 40];
        const float4 cA = *(const float4*)&cosb[(s0 + r) * HD + d];
        const float4 cB = *(const float4*)&cosb[(s0 + r) * HD + d + 4];
        const float4 sA = *(const float4*)&sinb[(s0 + r) * HD + d];
        const float4 sB = *(const float4*)&sinb[(s0 + r) * HD + d + 4];
        half8 qo0, qo1, ko0, ko1;
#pragma unroll
        for (int j = 0; j < 8; j++) {
            const float cj = (j < 4) ? cA[j] : cB[j - 4];
            const float sj = (j < 4) ? sA[j] : sB[j - 4];
            qo0[j] = (_Float16)(((float)q0[j] * cj - (float)q1[j] * sj) * QSCALE_LOG2E);
            qo1[j] = (_Float16)(((float)q1[j] * cj + (float)q0[j] * sj) * QSCALE_LOG2E);
            ko0[j] = (_Float16)((float)k0[j] * cj - (float)k1[j] * sj);
            ko1[j] = (_Float16)((float)k1[j] * cj + (float)k0[j] * sj);
        }
        const long o = ((long)h * SEQLEN + s0 + r) * HDP;
        *(half8*)&Qh[o + d]      = qo0;
        *(half8*)&Qh[o + d + 40] = qo1;
        *(half8*)&Kh[o + d]      = ko0;
        *(half8*)&Kh[o + d + 40] = ko1;
    }
    // zero pads d in [80,96)
    for (int i = tid; i < 128; i += 256) {
        const int r = i >> 1, off = HD + (i & 1) * 8;
        const long o = ((long)h * SEQLEN + s0 + r) * HDP + off;
        *(half8*)&Qh[o] = (half8)(_Float16)0.f;
        *(half8*)&Kh[o] = (half8)(_Float16)0.f;
    }
    __syncthreads();
    // transposed V out: 80 d-rows x 8 s-chunks
    for (int i = tid; i < 640; i += 256) {
        const int d = i >> 3, sc = (i & 7) * 8;
        half8 v;
#pragma unroll
        for (int j = 0; j < 8; j++) v[j] = Ts[(sc + j) * 88 + d];
        *(half8*)&Vt[((long)h * HD + d) * SEQLEN + s0 + sc] = v;
    }
}

// ---------------------------------------------------------------------------
// Flash attention, transposed dataflow, fixed-max base-2 softmax, KV-split x4.
// 512-thread blocks: 8 waves x 16 q-rows = 128 q-rows/block; 64-key tiles.
//
// S^T = mfma_16x16x32(K_frag, Q_frag): lane holds query=l15, keys=quad*4+r.
// P^T = exp2(S^T) feeds PV directly as the 16x16x16 B-operand.
// V fragment-major: VF[nt][lane][fragment], row stride 24 halves (12 dw) so
// the per-lane half8 reads start at banks {0,12,24,4,16,28,8,20} — all 32
// banks covered uniformly (stride 16 was 2x-conflicted: half the banks idle).
// LDS 13.0 + 15.4 = 28.4 KB -> 4 blocks/CU, grid 1024 exactly resident.
__global__ __launch_bounds__(512, 8)
void attn_kernel(const _Float16* __restrict__ Qh, const _Float16* __restrict__ Kh,
                 const _Float16* __restrict__ Vt,
                 _Float16* __restrict__ Ohat0, _Float16* __restrict__ Ohat1,
                 float* __restrict__ Lpart) {
    const int s0 = blockIdx.x * 128;
    const int h  = blockIdx.y;
    const int z  = blockIdx.z;
    __shared__ __align__(16) _Float16 Ks[64 * KSTRIDE];        // 13.0 KB
    __shared__ __align__(16) _Float16 VF[5 * 64 * VFSTRIDE];   // 15.4 KB

    const int tid  = threadIdx.x;
    const int lane = tid & 63;
    const int wave = tid >> 6;
    const int l15  = lane & 15;
    const int quad = lane >> 4;

    const _Float16* Qg = Qh + ((long)h * SEQLEN + s0 + wave * 16 + l15) * HDP;
    half8 qf[3];
#pragma unroll
    for (int kk = 0; kk < 3; kk++)
        qf[kk] = *(const half8*)&Qg[kk * 32 + quad * 8];

    f32x4 oaccT[5] = {};
    float l_acc = 0.f;

    for (int t0 = z * KVSPAN; t0 < (z + 1) * KVSPAN; t0 += 64) {
        __syncthreads();
        const _Float16* Kg = Kh + ((long)h * SEQLEN + t0) * HDP;
        for (int i = tid; i < 768; i += 512) {       // 64 rows x 12 chunks
            const int r = i / 12, c = (i - r * 12) * 8;
            *(half8*)&Ks[r * KSTRIDE + c] = *(const half8*)&Kg[(long)r * HDP + c];
        }
        const _Float16* Vtg = Vt + (long)h * HD * SEQLEN + t0;
        for (int i = tid; i < 640; i += 512) {       // 80 d-rows x 8 chunks
            const int d = i >> 3, c = (i & 7) * 8;
            const half8 v = *(const half8*)&Vtg[(long)d * SEQLEN + c];
            const int nt = d >> 4, ld = d & 15;
            const int ct = c >> 4, qb = (c & 15) >> 2;   // qb in {0, 2}
            *(half4*)&VF[(nt * 64 + qb * 16 + ld) * VFSTRIDE + ct * 4]       = lo4(v);
            *(half4*)&VF[(nt * 64 + (qb + 1) * 16 + ld) * VFSTRIDE + ct * 4] = hi4(v);
        }
        __syncthreads();

        // S^T: 4 col-tiles of 16 keys each (operands swapped: A=K, B=Q)
        f32x4 sa[4] = {};
#pragma unroll
        for (int kk = 0; kk < 3; kk++)
#pragma unroll
            for (int ct = 0; ct < 4; ct++) {
                half8 kf = *(const half8*)&Ks[(ct * 16 + l15) * KSTRIDE + kk * 32 + quad * 8];
                sa[ct] = mfma_16x16x32(kf, qf[kk], sa[ct]);
            }

        // P^T = exp2(S^T) straight into 16x16x16 B-operand registers
        half4 pb[4];
#pragma unroll
        for (int ct = 0; ct < 4; ct++)
#pragma unroll
            for (int r = 0; r < 4; r++) {
                const float p = EXP2F(sa[ct][r]);
                l_acc += p;
                pb[ct][r] = (_Float16)p;
            }

        // O^T += V^T * P^T : 2 lane-contiguous half8 reads per nt
#pragma unroll
        for (int nt = 0; nt < 5; nt++) {
            const half8 va = *(const half8*)&VF[(nt * 64 + lane) * VFSTRIDE];
            const half8 vb = *(const half8*)&VF[(nt * 64 + lane) * VFSTRIDE + 8];
            oaccT[nt] = mfma_16x16x16(lo4(va), pb[0], oaccT[nt]);
            oaccT[nt] = mfma_16x16x16(hi4(va), pb[1], oaccT[nt]);
            oaccT[nt] = mfma_16x16x16(lo4(vb), pb[2], oaccT[nt]);
            oaccT[nt] = mfma_16x16x16(hi4(vb), pb[3], oaccT[nt]);
        }
    }

    // l: sum the 4 quads holding this query's key-chunks
    l_acc += __shfl_xor(l_acc, 16);
    l_acc += __shfl_xor(l_acc, 32);
    const float inv = 1.0f / l_acc;

    // partials: z 0,1 -> Ohat0 region, z 2,3 -> Ohat1 region
    _Float16* Oz = (z < 2) ? Ohat0 : Ohat1;
    const long obase = ((long)(z & 1) * NHEADS + h) * SEQLEN;
    const long lbase = ((long)z * NHEADS + h) * SEQLEN;
    const long row = s0 + wave * 16 + l15;           // this lane's query
#pragma unroll
    for (int nt = 0; nt < 5; nt++) {
        half4 o;
#pragma unroll
        for (int r = 0; r < 4; r++) o[r] = (_Float16)(oaccT[nt][r] * inv);
        *(half4*)&Oz[(obase + row) * HD + nt * 16 + quad * 4] = o;
    }
    if (quad == 0)
        Lpart[lbase + row] = l_acc;
}

// ---------------------------------------------------------------------------
// out = sum_z Ohat_z * l_z / sum_z l_z  -> attnb f16 [s][h*80+d]
__global__ __launch_bounds__(256)
void attn_combine(const _Float16* __restrict__ Ohat0,
                  const _Float16* __restrict__ Ohat1,
                  const float* __restrict__ Lp,
                  _Float16* __restrict__ attnb) {
    const int i = blockIdx.x * 256 + threadIdx.x;
    if (i >= SEQLEN * DIMM / 4) return;
    const int flat = i * 4;
    const int s = flat / DIMM;
    const int rem = flat - s * DIMM;
    const int h = rem / HD;
    const int d = rem - h * HD;
    float l[NSPLIT], lsum = 0.f;
#pragma unroll
    for (int zi = 0; zi < NSPLIT; zi++) {
        l[zi] = Lp[((long)zi * NHEADS + h) * SEQLEN + s];
        lsum += l[zi];
    }
    const float invl = 1.0f / lsum;
    float acc[4] = {0.f, 0.f, 0.f, 0.f};
#pragma unroll
    for (int zi = 0; zi < NSPLIT; zi++) {
        const _Float16* Oz = (zi < 2) ? Ohat0 : Ohat1;
        const long obase = ((long)(zi & 1) * NHEADS + h) * SEQLEN;
        const half4 o = *(const half4*)&Oz[(obase + s) * HD + d];
        const float w = l[zi] * invl;
#pragma unroll
        for (int j = 0; j < 4; j++) acc[j] += (float)o[j] * w;
    }
    half4 o;
#pragma unroll
    for (int j = 0; j < 4; j++) o[j] = (_Float16)acc[j];
    *(half4*)&attnb[(long)s * DIMM + rem] = o;
}

// ---------------------------------------------------------------------------
extern "C" void kernel_launch(void* const* d_in, const int* in_sizes, int n_in,
                              void* d_out, int out_size, void* d_ws, size_t ws_size,
                              hipStream_t stream) {
    const float* hs     = (const float*)d_in[0];
    // d_in[1] = cu_seqlens [0, 2048] — reference does no masking; unused.
    const float* cosb   = (const float*)d_in[2];
    const float* sinb   = (const float*)d_in[3];
    const float* w_qkv  = (const float*)d_in[4];
    const float* b_qkv  = (const float*)d_in[5];
    const float* w_proj = (const float*)d_in[6];
    const float* b_proj = (const float*)d_in[7];
    float* out = (float*)d_out;

    _Float16* hsb    = (_Float16*)d_ws;                       // 2048*1280
    _Float16* wqkvb  = hsb    + (long)SEQLEN * DIMM;          // 3840*1280
    _Float16* wprojb = wqkvb  + (long)QKV_N * DIMM;           // 1280*1280
    _Float16* qkv    = wprojb + (long)DIMM * DIMM;            // 2048*3840
    _Float16* Qh     = qkv    + (long)SEQLEN * QKV_N;         // 16*2048*96
    _Float16* Kh     = Qh     + (long)NHEADS * SEQLEN * HDP;
    _Float16* Vtb    = Kh     + (long)NHEADS * SEQLEN * HDP;  // 16*80*2048
    _Float16* attnb  = Vtb    + (long)NHEADS * HD * SEQLEN;   // 2048*1280

    // attention partials alias DEAD regions during attention:
    //   Ohat0 (z=0,1): hsb+wqkvb region (15.07 MB) — dead after QKV GEMM.
    //   Ohat1 (z=2,3): qkv region (15.73 MB) — dead after rope_repack_t.
    _Float16* Ohat0  = (_Float16*)d_ws;
    float*    LpartB = (float*)(Ohat0 + (long)2 * NHEADS * SEQLEN * HD);
    _Float16* Ohat1  = qkv;

    {
        const int ntot = (SEQLEN * DIMM + QKV_N * DIMM + DIMM * DIMM) / 4;
        cast_all<<<(ntot + 255) / 256, 256, 0, stream>>>(
            hs, w_qkv, w_proj, hsb, wqkvb, wprojb);
    }

    gemm_bt<true><<<dim3(SEQLEN / 128, QKV_N / 128), 256, 0, stream>>>(
        hsb, wqkvb, b_qkv, qkv, SEQLEN, QKV_N, DIMM);

    rope_repack_t<<<dim3(SEQLEN / 64, NHEADS), 256, 0, stream>>>(
        qkv, cosb, sinb, Qh, Kh, Vtb);

    attn_kernel<<<dim3(SEQLEN / 128, NHEADS, NSPLIT), 512, 0, stream>>>(
        Qh, Kh, Vtb, Ohat0, Ohat1, LpartB);

    attn_combine<<<(SEQLEN * DIMM / 4 + 255) / 256, 256, 0, stream>>>(
        Ohat0, Ohat1, LpartB, attnb);

    gemm_bt<false><<<dim3(SEQLEN / 128, DIMM / 128), 256, 0, stream>>>(
        attnb, wprojb, b_proj, out, SEQLEN, DIMM, DIMM);
}

// Round 11
// 207.345 us; speedup vs baseline: 1.0575x; 1.0229x over previous
//
#include <hip/hip_runtime.h>

// ---------------------------------------------------------------------------
// SimpleVisionAttention on MI355X (gfx950)
// S=2048, DIM=1280 (16 heads x 80), fp32 in/out, f16 MFMA internally.
//
// Pipeline:
//   K1  fused cast fp32 -> f16   (hs, w_qkv, w_proj)
//   K2  QKV GEMM  64x128 tiles (960 blocks: grid-fill beats per-block eff.)
//   K3  fused RoPE + repack Qh/Kh [h][s][96] + V transpose -> Vt[h][d][s]
//   K4  flash attention, transposed dataflow (S^T->P^T in regs), fixed-max
//       base-2 softmax, KV-split x4, fragment-major V (stride 24)
//   K4b combine 4 partials (weighted by per-split l)
//   K5  proj GEMM 64x128 tiles (320 blocks vs 160: was 0.625 blocks/CU)
// ---------------------------------------------------------------------------

#define SEQLEN   2048
#define DIMM     1280
#define NHEADS   16
#define HD       80
#define HDP      96          // padded head dim for Q/K (3 x 32 mfma K-steps)
#define QKV_N    3840
#define NSPLIT   4
#define KVSPAN   (SEQLEN / NSPLIT)
// SCALE * log2(e) folded into Q at rope time; softmax done in base-2.
#define QSCALE_LOG2E 0.16130083587064776f   // 80^-0.5 * 1.4426950408889634

#define KSTRIDE  104  // K-tile row stride (52 dw): read starts uniform
#define VFSTRIDE 24   // VF row stride (12 dw): lane starts cover all 32 banks

// device base-2 exp: v_exp_f32 (NOT __exp2f — collides with glibc math.h)
#define EXP2F(x) __builtin_amdgcn_exp2f(x)

// async global->LDS, 16B per lane; LDS dest must be waveBase + lane*16
#define GLD16(gptr, lptr)                                                      \
    __builtin_amdgcn_global_load_lds(                                          \
        (const __attribute__((address_space(1))) void*)(gptr),                 \
        (__attribute__((address_space(3))) void*)(lptr), 16, 0, 0)

typedef float f32x4 __attribute__((ext_vector_type(4)));
typedef _Float16 half8 __attribute__((ext_vector_type(8)));
typedef _Float16 half4 __attribute__((ext_vector_type(4)));

static __device__ __forceinline__ f32x4 mfma_16x16x32(half8 a, half8 b, f32x4 c) {
    return __builtin_amdgcn_mfma_f32_16x16x32_f16(a, b, c, 0, 0, 0);
}
// NOTE: legacy K=16 shape is spelled WITHOUT the underscore: ...16x16x16f16
static __device__ __forceinline__ f32x4 mfma_16x16x16(half4 a, half4 b, f32x4 c) {
    return __builtin_amdgcn_mfma_f32_16x16x16f16(a, b, c, 0, 0, 0);
}
static __device__ __forceinline__ half4 lo4(half8 v) {
    return __builtin_shufflevector(v, v, 0, 1, 2, 3);
}
static __device__ __forceinline__ half4 hi4(half8 v) {
    return __builtin_shufflevector(v, v, 4, 5, 6, 7);
}

// ---------------------------------------------------------------------------
// One fused cast kernel for the three fp32->f16 conversions.
__global__ __launch_bounds__(256)
void cast_all(const float* __restrict__ hs, const float* __restrict__ wq,
              const float* __restrict__ wp, _Float16* __restrict__ dhs,
              _Float16* __restrict__ dwq, _Float16* __restrict__ dwp) {
    const int n1 = SEQLEN * DIMM / 4, n2 = QKV_N * DIMM / 4, n3 = DIMM * DIMM / 4;
    int i = blockIdx.x * 256 + threadIdx.x;
    const float4* src; half4* dst; int j;
    if (i < n1)           { src = (const float4*)hs; dst = (half4*)dhs; j = i; }
    else if (i < n1 + n2) { src = (const float4*)wq; dst = (half4*)dwq; j = i - n1; }
    else if (i < n1 + n2 + n3) { src = (const float4*)wp; dst = (half4*)dwp; j = i - n1 - n2; }
    else return;
    const float4 v = src[j];
    half4 h;
    h.x = (_Float16)v.x; h.y = (_Float16)v.y;
    h.z = (_Float16)v.z; h.w = (_Float16)v.w;
    dst[j] = h;
}

// ---------------------------------------------------------------------------
// C[m][n] = sum_k A[m][k] * B[n][k] + bias[n]
// A: M x K f16 row-major, B: N x K f16 row-major (i.e. B^T layout).
// 64x128 block tile, BK=32, 4 waves 2x2 (each 32x64, 2x4 mfma tiles).
// Small tile -> 2-6x more blocks than 128x128: fills the 256-CU grid
// (proj was 160 blocks = 0.625/CU with the big tile; QKV 480 = 1.875/CU).
// Staging: A = 4 chunks (64r x 32c), B = 8 chunks (128r x 32c); wave w
// stages A-chunk w + B-chunks {w, w+4} via async global_load_lds.
template<bool OUT_F16>
__global__ __launch_bounds__(256, 2)
void gemm_bt64(const _Float16* __restrict__ A, const _Float16* __restrict__ B,
               const float* __restrict__ bias, void* __restrict__ Cout,
               int M, int N, int K) {
    __shared__ __align__(16) _Float16 As[64 * 32];    // 4 KB
    __shared__ __align__(16) _Float16 Bs[128 * 32];   // 8 KB
    const int tid  = threadIdx.x;
    const int lane = tid & 63;
    const int wave = tid >> 6;
    const int l15  = lane & 15;
    const int quad = lane >> 4;
    const int wm   = wave & 1;
    const int wn   = wave >> 1;
    const long bm = blockIdx.x, bn = blockIdx.y;

    const _Float16* Ag = A + bm * 64 * (long)K;
    const _Float16* Bg = B + bn * 128 * (long)K;

    const int srow = lane >> 2;            // 0..15 within chunk
    const int scol = (lane & 3) * 8;       // halves
    f32x4 acc[2][4] = {};

    for (int k0 = 0; k0 < K; k0 += 32) {
        __syncthreads();
        {
            const long arow = 16 * wave + srow;
            GLD16(Ag + arow * K + k0 + scol, As + 512 * wave + lane * 8);
#pragma unroll
            for (int cc = 0; cc < 2; cc++) {
                const int c = wave + cc * 4;
                const long brow = 16 * c + srow;
                GLD16(Bg + brow * K + k0 + scol, Bs + 512 * c + lane * 8);
            }
        }
        __syncthreads();
        half8 af[2], bf[4];
#pragma unroll
        for (int t = 0; t < 2; t++)
            af[t] = *(const half8*)&As[(wm * 32 + t * 16 + l15) * 32 + quad * 8];
#pragma unroll
        for (int t = 0; t < 4; t++)
            bf[t] = *(const half8*)&Bs[(wn * 64 + t * 16 + l15) * 32 + quad * 8];
#pragma unroll
        for (int mt = 0; mt < 2; mt++)
#pragma unroll
            for (int nt = 0; nt < 4; nt++)
                acc[mt][nt] = mfma_16x16x32(af[mt], bf[nt], acc[mt][nt]);
    }

    float bv[4];
#pragma unroll
    for (int nt = 0; nt < 4; nt++)
        bv[nt] = bias[bn * 128 + wn * 64 + nt * 16 + l15];

#pragma unroll
    for (int mt = 0; mt < 2; mt++) {
#pragma unroll
        for (int r = 0; r < 4; r++) {
            const long row = bm * 64 + wm * 32 + mt * 16 + quad * 4 + r;
#pragma unroll
            for (int nt = 0; nt < 4; nt++) {
                const long col = bn * 128 + wn * 64 + nt * 16 + l15;
                const float v = acc[mt][nt][r] + bv[nt];
                if (OUT_F16) ((_Float16*)Cout)[row * (long)N + col] = (_Float16)v;
                else         ((float*)Cout)[row * (long)N + col] = v;
            }
        }
    }
}

// ---------------------------------------------------------------------------
// Fused: RoPE on q,k -> Qh/Kh [h][s][96] (Q pre-scaled by SCALE*log2e, pads
// zeroed) + V transposed via LDS -> Vt[h][d][s]. Block = (64 seqs, 1 head).
__global__ __launch_bounds__(256)
void rope_repack_t(const _Float16* __restrict__ qkv,
                   const float* __restrict__ cosb,
                   const float* __restrict__ sinb,
                   _Float16* __restrict__ Qh,
                   _Float16* __restrict__ Kh,
                   _Float16* __restrict__ Vt) {
    const int s0 = blockIdx.x * 64;
    const int h  = blockIdx.y;
    __shared__ __align__(16) _Float16 Ts[64 * 88];
    const int tid = threadIdx.x;

    // stage V rows into LDS (transposed write later)
    for (int i = tid; i < 640; i += 256) {          // 64 rows x 10 chunks
        const int r = i / 10, c = (i - r * 10) * 8;
        *(half8*)&Ts[r * 88 + c] =
            *(const half8*)&qkv[(long)(s0 + r) * QKV_N + 2 * DIMM + h * HD + c];
    }

    // q,k rope: 64 rows x 5 chunks of 8 (d in [0,40))
    for (int i = tid; i < 320; i += 256) {
        const int r = i / 5, d = (i - r * 5) * 8;
        const _Float16* row = qkv + (long)(s0 + r) * QKV_N + h * HD;
        const half8 q0 = *(const half8*)&row[d];
        const half8 q1 = *(const half8*)&row[d + 40];
        const half8 k0 = *(const half8*)&row[DIMM + d];
        const half8 k1 = *(const half8*)&row[DIMM + d + 40];
        const float4 cA = *(const float4*)&cosb[(s0 + r) * HD + d];
        const float4 cB = *(const float4*)&cosb[(s0 + r) * HD + d + 4];
        const float4 sA = *(const float4*)&sinb[(s0 + r) * HD + d];
        const float4 sB = *(const float4*)&sinb[(s0 + r) * HD + d + 4];
        half8 qo0, qo1, ko0, ko1;
#pragma unroll
        for (int j = 0; j < 8; j++) {
            const float cj = (j < 4) ? cA[j] : cB[j - 4];
            const float sj = (j < 4) ? sA[j] : sB[j - 4];
            qo0[j] = (_Float16)(((float)q0[j] * cj - (float)q1[j] * sj) * QSCALE_LOG2E);
            qo1[j] = (_Float16)(((float)q1[j] * cj + (float)q0[j] * sj) * QSCALE_LOG2E);
            ko0[j] = (_Float16)((float)k0[j] * cj - (float)k1[j] * sj);
            ko1[j] = (_Float16)((float)k1[j] * cj + (float)k0[j] * sj);
        }
        const long o = ((long)h * SEQLEN + s0 + r) * HDP;
        *(half8*)&Qh[o + d]      = qo0;
        *(half8*)&Qh[o + d + 40] = qo1;
        *(half8*)&Kh[o + d]      = ko0;
        *(half8*)&Kh[o + d + 40] = ko1;
    }
    // zero pads d in [80,96)
    for (int i = tid; i < 128; i += 256) {
        const int r = i >> 1, off = HD + (i & 1) * 8;
        const long o = ((long)h * SEQLEN + s0 + r) * HDP + off;
        *(half8*)&Qh[o] = (half8)(_Float16)0.f;
        *(half8*)&Kh[o] = (half8)(_Float16)0.f;
    }
    __syncthreads();
    // transposed V out: 80 d-rows x 8 s-chunks
    for (int i = tid; i < 640; i += 256) {
        const int d = i >> 3, sc = (i & 7) * 8;
        half8 v;
#pragma unroll
        for (int j = 0; j < 8; j++) v[j] = Ts[(sc + j) * 88 + d];
        *(half8*)&Vt[((long)h * HD + d) * SEQLEN + s0 + sc] = v;
    }
}

// ---------------------------------------------------------------------------
// Flash attention, transposed dataflow, fixed-max base-2 softmax, KV-split x4.
// 512-thread blocks: 8 waves x 16 q-rows = 128 q-rows/block; 64-key tiles.
// S^T = mfma_16x16x32(K_frag, Q_frag); P^T = exp2(S^T) feeds PV directly as
// the 16x16x16 B-operand (no LDS round-trip). V fragment-major, stride 24.
// LDS 28.4 KB -> 4 blocks/CU, grid 1024 exactly resident.
__global__ __launch_bounds__(512, 8)
void attn_kernel(const _Float16* __restrict__ Qh, const _Float16* __restrict__ Kh,
                 const _Float16* __restrict__ Vt,
                 _Float16* __restrict__ Ohat0, _Float16* __restrict__ Ohat1,
                 float* __restrict__ Lpart) {
    const int s0 = blockIdx.x * 128;
    const int h  = blockIdx.y;
    const int z  = blockIdx.z;
    __shared__ __align__(16) _Float16 Ks[64 * KSTRIDE];        // 13.0 KB
    __shared__ __align__(16) _Float16 VF[5 * 64 * VFSTRIDE];   // 15.4 KB

    const int tid  = threadIdx.x;
    const int lane = tid & 63;
    const int wave = tid >> 6;
    const int l15  = lane & 15;
    const int quad = lane >> 4;

    const _Float16* Qg = Qh + ((long)h * SEQLEN + s0 + wave * 16 + l15) * HDP;
    half8 qf[3];
#pragma unroll
    for (int kk = 0; kk < 3; kk++)
        qf[kk] = *(const half8*)&Qg[kk * 32 + quad * 8];

    f32x4 oaccT[5] = {};
    float l_acc = 0.f;

    for (int t0 = z * KVSPAN; t0 < (z + 1) * KVSPAN; t0 += 64) {
        __syncthreads();
        const _Float16* Kg = Kh + ((long)h * SEQLEN + t0) * HDP;
        for (int i = tid; i < 768; i += 512) {       // 64 rows x 12 chunks
            const int r = i / 12, c = (i - r * 12) * 8;
            *(half8*)&Ks[r * KSTRIDE + c] = *(const half8*)&Kg[(long)r * HDP + c];
        }
        const _Float16* Vtg = Vt + (long)h * HD * SEQLEN + t0;
        for (int i = tid; i < 640; i += 512) {       // 80 d-rows x 8 chunks
            const int d = i >> 3, c = (i & 7) * 8;
            const half8 v = *(const half8*)&Vtg[(long)d * SEQLEN + c];
            const int nt = d >> 4, ld = d & 15;
            const int ct = c >> 4, qb = (c & 15) >> 2;   // qb in {0, 2}
            *(half4*)&VF[(nt * 64 + qb * 16 + ld) * VFSTRIDE + ct * 4]       = lo4(v);
            *(half4*)&VF[(nt * 64 + (qb + 1) * 16 + ld) * VFSTRIDE + ct * 4] = hi4(v);
        }
        __syncthreads();

        // S^T: 4 col-tiles of 16 keys each (operands swapped: A=K, B=Q)
        f32x4 sa[4] = {};
#pragma unroll
        for (int kk = 0; kk < 3; kk++)
#pragma unroll
            for (int ct = 0; ct < 4; ct++) {
                half8 kf = *(const half8*)&Ks[(ct * 16 + l15) * KSTRIDE + kk * 32 + quad * 8];
                sa[ct] = mfma_16x16x32(kf, qf[kk], sa[ct]);
            }

        // P^T = exp2(S^T) straight into 16x16x16 B-operand registers
        half4 pb[4];
#pragma unroll
        for (int ct = 0; ct < 4; ct++)
#pragma unroll
            for (int r = 0; r < 4; r++) {
                const float p = EXP2F(sa[ct][r]);
                l_acc += p;
                pb[ct][r] = (_Float16)p;
            }

        // O^T += V^T * P^T : 2 lane-contiguous half8 reads per nt
#pragma unroll
        for (int nt = 0; nt < 5; nt++) {
            const half8 va = *(const half8*)&VF[(nt * 64 + lane) * VFSTRIDE];
            const half8 vb = *(const half8*)&VF[(nt * 64 + lane) * VFSTRIDE + 8];
            oaccT[nt] = mfma_16x16x16(lo4(va), pb[0], oaccT[nt]);
            oaccT[nt] = mfma_16x16x16(hi4(va), pb[1], oaccT[nt]);
            oaccT[nt] = mfma_16x16x16(lo4(vb), pb[2], oaccT[nt]);
            oaccT[nt] = mfma_16x16x16(hi4(vb), pb[3], oaccT[nt]);
        }
    }

    // l: sum the 4 quads holding this query's key-chunks
    l_acc += __shfl_xor(l_acc, 16);
    l_acc += __shfl_xor(l_acc, 32);
    const float inv = 1.0f / l_acc;

    // partials: z 0,1 -> Ohat0 region, z 2,3 -> Ohat1 region
    _Float16* Oz = (z < 2) ? Ohat0 : Ohat1;
    const long obase = ((long)(z & 1) * NHEADS + h) * SEQLEN;
    const long lbase = ((long)z * NHEADS + h) * SEQLEN;
    const long row = s0 + wave * 16 + l15;           // this lane's query
#pragma unroll
    for (int nt = 0; nt < 5; nt++) {
        half4 o;
#pragma unroll
        for (int r = 0; r < 4; r++) o[r] = (_Float16)(oaccT[nt][r] * inv);
        *(half4*)&Oz[(obase + row) * HD + nt * 16 + quad * 4] = o;
    }
    if (quad == 0)
        Lpart[lbase + row] = l_acc;
}

// ---------------------------------------------------------------------------
// out = sum_z Ohat_z * l_z / sum_z l_z  -> attnb f16 [s][h*80+d]
__global__ __launch_bounds__(256)
void attn_combine(const _Float16* __restrict__ Ohat0,
                  const _Float16* __restrict__ Ohat1,
                  const float* __restrict__ Lp,
                  _Float16* __restrict__ attnb) {
    const int i = blockIdx.x * 256 + threadIdx.x;
    if (i >= SEQLEN * DIMM / 4) return;
    const int flat = i * 4;
    const int s = flat / DIMM;
    const int rem = flat - s * DIMM;
    const int h = rem / HD;
    const int d = rem - h * HD;
    float l[NSPLIT], lsum = 0.f;
#pragma unroll
    for (int zi = 0; zi < NSPLIT; zi++) {
        l[zi] = Lp[((long)zi * NHEADS + h) * SEQLEN + s];
        lsum += l[zi];
    }
    const float invl = 1.0f / lsum;
    float acc[4] = {0.f, 0.f, 0.f, 0.f};
#pragma unroll
    for (int zi = 0; zi < NSPLIT; zi++) {
        const _Float16* Oz = (zi < 2) ? Ohat0 : Ohat1;
        const long obase = ((long)(zi & 1) * NHEADS + h) * SEQLEN;
        const half4 o = *(const half4*)&Oz[(obase + s) * HD + d];
        const float w = l[zi] * invl;
#pragma unroll
        for (int j = 0; j < 4; j++) acc[j] += (float)o[j] * w;
    }
    half4 o;
#pragma unroll
    for (int j = 0; j < 4; j++) o[j] = (_Float16)acc[j];
    *(half4*)&attnb[(long)s * DIMM + rem] = o;
}

// ---------------------------------------------------------------------------
extern "C" void kernel_launch(void* const* d_in, const int* in_sizes, int n_in,
                              void* d_out, int out_size, void* d_ws, size_t ws_size,
                              hipStream_t stream) {
    const float* hs     = (const float*)d_in[0];
    // d_in[1] = cu_seqlens [0, 2048] — reference does no masking; unused.
    const float* cosb   = (const float*)d_in[2];
    const float* sinb   = (const float*)d_in[3];
    const float* w_qkv  = (const float*)d_in[4];
    const float* b_qkv  = (const float*)d_in[5];
    const float* w_proj = (const float*)d_in[6];
    const float* b_proj = (const float*)d_in[7];
    float* out = (float*)d_out;

    _Float16* hsb    = (_Float16*)d_ws;                       // 2048*1280
    _Float16* wqkvb  = hsb    + (long)SEQLEN * DIMM;          // 3840*1280
    _Float16* wprojb = wqkvb  + (long)QKV_N * DIMM;           // 1280*1280
    _Float16* qkv    = wprojb + (long)DIMM * DIMM;            // 2048*3840
    _Float16* Qh     = qkv    + (long)SEQLEN * QKV_N;         // 16*2048*96
    _Float16* Kh     = Qh     + (long)NHEADS * SEQLEN * HDP;
    _Float16* Vtb    = Kh     + (long)NHEADS * SEQLEN * HDP;  // 16*80*2048
    _Float16* attnb  = Vtb    + (long)NHEADS * HD * SEQLEN;   // 2048*1280

    // attention partials alias DEAD regions during attention:
    //   Ohat0 (z=0,1): hsb+wqkvb region (15.07 MB) — dead after QKV GEMM.
    //   Ohat1 (z=2,3): qkv region (15.73 MB) — dead after rope_repack_t.
    _Float16* Ohat0  = (_Float16*)d_ws;
    float*    LpartB = (float*)(Ohat0 + (long)2 * NHEADS * SEQLEN * HD);
    _Float16* Ohat1  = qkv;

    {
        const int ntot = (SEQLEN * DIMM + QKV_N * DIMM + DIMM * DIMM) / 4;
        cast_all<<<(ntot + 255) / 256, 256, 0, stream>>>(
            hs, w_qkv, w_proj, hsb, wqkvb, wprojb);
    }

    gemm_bt64<true><<<dim3(SEQLEN / 64, QKV_N / 128), 256, 0, stream>>>(
        hsb, wqkvb, b_qkv, qkv, SEQLEN, QKV_N, DIMM);

    rope_repack_t<<<dim3(SEQLEN / 64, NHEADS), 256, 0, stream>>>(
        qkv, cosb, sinb, Qh, Kh, Vtb);

    attn_kernel<<<dim3(SEQLEN / 128, NHEADS, NSPLIT), 512, 0, stream>>>(
        Qh, Kh, Vtb, Ohat0, Ohat1, LpartB);

    attn_combine<<<(SEQLEN * DIMM / 4 + 255) / 256, 256, 0, stream>>>(
        Ohat0, Ohat1, LpartB, attnb);

    gemm_bt64<false><<<dim3(SEQLEN / 64, DIMM / 128), 256, 0, stream>>>(
        attnb, wprojb, b_proj, out, SEQLEN, DIMM, DIMM);
}

// Round 13
// 207.194 us; speedup vs baseline: 1.0583x; 1.0007x over previous
//
#include <hip/hip_runtime.h>

// ---------------------------------------------------------------------------
// SimpleVisionAttention on MI355X (gfx950)
// S=2048, DIM=1280 (16 heads x 80), fp32 in/out, f16 MFMA internally.
//
// Pipeline:
//   K1  fused cast fp32 -> f16   (hs, w_qkv, w_proj)
//   K2  QKV GEMM  64x128 tiles, BK=64 dual-panel (half the barriers of BK=32)
//   K3  fused RoPE + repack Qh/Kh [h][s][96] + V transpose -> Vt[h][d][s]
//   K4  flash attention, transposed dataflow (S^T->P^T in regs), fixed-max
//       base-2 softmax, KV-split x4, fragment-major V (stride 24)
//   K4b combine 4 partials (weighted by per-split l)
//   K5  proj GEMM 64x128 tiles, BK=64 dual-panel
// ---------------------------------------------------------------------------

#define SEQLEN   2048
#define DIMM     1280
#define NHEADS   16
#define HD       80
#define HDP      96          // padded head dim for Q/K (3 x 32 mfma K-steps)
#define QKV_N    3840
#define NSPLIT   4
#define KVSPAN   (SEQLEN / NSPLIT)
// SCALE * log2(e) folded into Q at rope time; softmax done in base-2.
#define QSCALE_LOG2E 0.16130083587064776f   // 80^-0.5 * 1.4426950408889634

#define KSTRIDE  104  // K-tile row stride (52 dw): read starts uniform
#define VFSTRIDE 24   // VF row stride (12 dw): lane starts cover all 32 banks

// device base-2 exp: v_exp_f32 (NOT __exp2f — collides with glibc math.h)
#define EXP2F(x) __builtin_amdgcn_exp2f(x)

// async global->LDS, 16B per lane; LDS dest must be waveBase + lane*16
#define GLD16(gptr, lptr)                                                      \
    __builtin_amdgcn_global_load_lds(                                          \
        (const __attribute__((address_space(1))) void*)(gptr),                 \
        (__attribute__((address_space(3))) void*)(lptr), 16, 0, 0)

typedef float f32x4 __attribute__((ext_vector_type(4)));
typedef _Float16 half8 __attribute__((ext_vector_type(8)));
typedef _Float16 half4 __attribute__((ext_vector_type(4)));

static __device__ __forceinline__ f32x4 mfma_16x16x32(half8 a, half8 b, f32x4 c) {
    return __builtin_amdgcn_mfma_f32_16x16x32_f16(a, b, c, 0, 0, 0);
}
// NOTE: legacy K=16 shape is spelled WITHOUT the underscore: ...16x16x16f16
static __device__ __forceinline__ f32x4 mfma_16x16x16(half4 a, half4 b, f32x4 c) {
    return __builtin_amdgcn_mfma_f32_16x16x16f16(a, b, c, 0, 0, 0);
}
static __device__ __forceinline__ half4 lo4(half8 v) {
    return __builtin_shufflevector(v, v, 0, 1, 2, 3);
}
static __device__ __forceinline__ half4 hi4(half8 v) {
    return __builtin_shufflevector(v, v, 4, 5, 6, 7);
}

// ---------------------------------------------------------------------------
// One fused cast kernel for the three fp32->f16 conversions.
__global__ __launch_bounds__(256)
void cast_all(const float* __restrict__ hs, const float* __restrict__ wq,
              const float* __restrict__ wp, _Float16* __restrict__ dhs,
              _Float16* __restrict__ dwq, _Float16* __restrict__ dwp) {
    const int n1 = SEQLEN * DIMM / 4, n2 = QKV_N * DIMM / 4, n3 = DIMM * DIMM / 4;
    int i = blockIdx.x * 256 + threadIdx.x;
    const float4* src; half4* dst; int j;
    if (i < n1)           { src = (const float4*)hs; dst = (half4*)dhs; j = i; }
    else if (i < n1 + n2) { src = (const float4*)wq; dst = (half4*)dwq; j = i - n1; }
    else if (i < n1 + n2 + n3) { src = (const float4*)wp; dst = (half4*)dwp; j = i - n1 - n2; }
    else return;
    const float4 v = src[j];
    half4 h;
    h.x = (_Float16)v.x; h.y = (_Float16)v.y;
    h.z = (_Float16)v.z; h.w = (_Float16)v.w;
    dst[j] = h;
}

// ---------------------------------------------------------------------------
// C[m][n] = sum_k A[m][k] * B[n][k] + bias[n]
// A: M x K f16 row-major, B: N x K f16 row-major (i.e. B^T layout).
// 64x128 block tile, 4 waves 2x2 (each 32x64, 2x4 mfma tiles).
// BK=64 as TWO BK=32 PANELS: keeps the LDS row stride at 32 halves (a flat
// 64-stride would put lane-strided ds_reads on one bank = 16-way conflict,
// and global_load_lds forbids padding). Halves barrier count vs BK=32:
// 20 K-iters x 2 barriers, 16 MFMA + 6 GLD16 + 12 ds_read_b128 per iter.
template<bool OUT_F16>
__global__ __launch_bounds__(256, 2)
void gemm_bt64(const _Float16* __restrict__ A, const _Float16* __restrict__ B,
               const float* __restrict__ bias, void* __restrict__ Cout,
               int M, int N, int K) {
    __shared__ __align__(16) _Float16 As[2][64 * 32];    // 8 KB
    __shared__ __align__(16) _Float16 Bs[2][128 * 32];   // 16 KB
    const int tid  = threadIdx.x;
    const int lane = tid & 63;
    const int wave = tid >> 6;
    const int l15  = lane & 15;
    const int quad = lane >> 4;
    const int wm   = wave & 1;
    const int wn   = wave >> 1;
    const long bm = blockIdx.x, bn = blockIdx.y;

    const _Float16* Ag = A + bm * 64 * (long)K;
    const _Float16* Bg = B + bn * 128 * (long)K;

    const int srow = lane >> 2;            // 0..15 within chunk
    const int scol = (lane & 3) * 8;       // halves
    f32x4 acc[2][4] = {};

    for (int k0 = 0; k0 < K; k0 += 64) {
        __syncthreads();
#pragma unroll
        for (int p = 0; p < 2; p++) {
            const int kp = k0 + p * 32;
            const long arow = 16 * wave + srow;
            GLD16(Ag + arow * K + kp + scol, &As[p][512 * wave + lane * 8]);
#pragma unroll
            for (int cc = 0; cc < 2; cc++) {
                const int c = wave + cc * 4;
                const long brow = 16 * c + srow;
                GLD16(Bg + brow * K + kp + scol, &Bs[p][512 * c + lane * 8]);
            }
        }
        __syncthreads();
#pragma unroll
        for (int p = 0; p < 2; p++) {
            half8 af[2], bf[4];
#pragma unroll
            for (int t = 0; t < 2; t++)
                af[t] = *(const half8*)&As[p][(wm * 32 + t * 16 + l15) * 32 + quad * 8];
#pragma unroll
            for (int t = 0; t < 4; t++)
                bf[t] = *(const half8*)&Bs[p][(wn * 64 + t * 16 + l15) * 32 + quad * 8];
#pragma unroll
            for (int mt = 0; mt < 2; mt++)
#pragma unroll
                for (int nt = 0; nt < 4; nt++)
                    acc[mt][nt] = mfma_16x16x32(af[mt], bf[nt], acc[mt][nt]);
        }
    }

    float bv[4];
#pragma unroll
    for (int nt = 0; nt < 4; nt++)
        bv[nt] = bias[bn * 128 + wn * 64 + nt * 16 + l15];

#pragma unroll
    for (int mt = 0; mt < 2; mt++) {
#pragma unroll
        for (int r = 0; r < 4; r++) {
            const long row = bm * 64 + wm * 32 + mt * 16 + quad * 4 + r;
#pragma unroll
            for (int nt = 0; nt < 4; nt++) {
                const long col = bn * 128 + wn * 64 + nt * 16 + l15;
                const float v = acc[mt][nt][r] + bv[nt];
                if (OUT_F16) ((_Float16*)Cout)[row * (long)N + col] = (_Float16)v;
                else         ((float*)Cout)[row * (long)N + col] = v;
            }
        }
    }
}

// ---------------------------------------------------------------------------
// Fused: RoPE on q,k -> Qh/Kh [h][s][96] (Q pre-scaled by SCALE*log2e, pads
// zeroed) + V transposed via LDS -> Vt[h][d][s]. Block = (64 seqs, 1 head).
__global__ __launch_bounds__(256)
void rope_repack_t(const _Float16* __restrict__ qkv,
                   const float* __restrict__ cosb,
                   const float* __restrict__ sinb,
                   _Float16* __restrict__ Qh,
                   _Float16* __restrict__ Kh,
                   _Float16* __restrict__ Vt) {
    const int s0 = blockIdx.x * 64;
    const int h  = blockIdx.y;
    __shared__ __align__(16) _Float16 Ts[64 * 88];
    const int tid = threadIdx.x;

    // stage V rows into LDS (transposed write later)
    for (int i = tid; i < 640; i += 256) {          // 64 rows x 10 chunks
        const int r = i / 10, c = (i - r * 10) * 8;
        *(half8*)&Ts[r * 88 + c] =
            *(const half8*)&qkv[(long)(s0 + r) * QKV_N + 2 * DIMM + h * HD + c];
    }

    // q,k rope: 64 rows x 5 chunks of 8 (d in [0,40))
    for (int i = tid; i < 320; i += 256) {
        const int r = i / 5, d = (i - r * 5) * 8;
        const _Float16* row = qkv + (long)(s0 + r) * QKV_N + h * HD;
        const half8 q0 = *(const half8*)&row[d];
        const half8 q1 = *(const half8*)&row[d + 40];
        const half8 k0 = *(const half8*)&row[DIMM + d];
        const half8 k1 = *(const half8*)&row[DIMM + d + 40];
        const float4 cA = *(const float4*)&cosb[(s0 + r) * HD + d];
        const float4 cB = *(const float4*)&cosb[(s0 + r) * HD + d + 4];
        const float4 sA = *(const float4*)&sinb[(s0 + r) * HD + d];
        const float4 sB = *(const float4*)&sinb[(s0 + r) * HD + d + 4];
        half8 qo0, qo1, ko0, ko1;
#pragma unroll
        for (int j = 0; j < 8; j++) {
            const float cj = (j < 4) ? cA[j] : cB[j - 4];
            const float sj = (j < 4) ? sA[j] : sB[j - 4];
            qo0[j] = (_Float16)(((float)q0[j] * cj - (float)q1[j] * sj) * QSCALE_LOG2E);
            qo1[j] = (_Float16)(((float)q1[j] * cj + (float)q0[j] * sj) * QSCALE_LOG2E);
            ko0[j] = (_Float16)((float)k0[j] * cj - (float)k1[j] * sj);
            ko1[j] = (_Float16)((float)k1[j] * cj + (float)k0[j] * sj);
        }
        const long o = ((long)h * SEQLEN + s0 + r) * HDP;
        *(half8*)&Qh[o + d]      = qo0;
        *(half8*)&Qh[o + d + 40] = qo1;
        *(half8*)&Kh[o + d]      = ko0;
        *(half8*)&Kh[o + d + 40] = ko1;
    }
    // zero pads d in [80,96)
    for (int i = tid; i < 128; i += 256) {
        const int r = i >> 1, off = HD + (i & 1) * 8;
        const long o = ((long)h * SEQLEN + s0 + r) * HDP + off;
        *(half8*)&Qh[o] = (half8)(_Float16)0.f;
        *(half8*)&Kh[o] = (half8)(_Float16)0.f;
    }
    __syncthreads();
    // transposed V out: 80 d-rows x 8 s-chunks
    for (int i = tid; i < 640; i += 256) {
        const int d = i >> 3, sc = (i & 7) * 8;
        half8 v;
#pragma unroll
        for (int j = 0; j < 8; j++) v[j] = Ts[(sc + j) * 88 + d];
        *(half8*)&Vt[((long)h * HD + d) * SEQLEN + s0 + sc] = v;
    }
}

// ---------------------------------------------------------------------------
// Flash attention, transposed dataflow, fixed-max base-2 softmax, KV-split x4.
// 512-thread blocks: 8 waves x 16 q-rows = 128 q-rows/block; 64-key tiles.
// S^T = mfma_16x16x32(K_frag, Q_frag); P^T = exp2(S^T) feeds PV directly as
// the 16x16x16 B-operand (no LDS round-trip). V fragment-major, stride 24.
// LDS 28.4 KB -> 4 blocks/CU, grid 1024 exactly resident.
__global__ __launch_bounds__(512, 8)
void attn_kernel(const _Float16* __restrict__ Qh, const _Float16* __restrict__ Kh,
                 const _Float16* __restrict__ Vt,
                 _Float16* __restrict__ Ohat0, _Float16* __restrict__ Ohat1,
                 float* __restrict__ Lpart) {
    const int s0 = blockIdx.x * 128;
    const int h  = blockIdx.y;
    const int z  = blockIdx.z;
    __shared__ __align__(16) _Float16 Ks[64 * KSTRIDE];        // 13.0 KB
    __shared__ __align__(16) _Float16 VF[5 * 64 * VFSTRIDE];   // 15.4 KB

    const int tid  = threadIdx.x;
    const int lane = tid & 63;
    const int wave = tid >> 6;
    const int l15  = lane & 15;
    const int quad = lane >> 4;

    const _Float16* Qg = Qh + ((long)h * SEQLEN + s0 + wave * 16 + l15) * HDP;
    half8 qf[3];
#pragma unroll
    for (int kk = 0; kk < 3; kk++)
        qf[kk] = *(const half8*)&Qg[kk * 32 + quad * 8];

    f32x4 oaccT[5] = {};
    float l_acc = 0.f;

    for (int t0 = z * KVSPAN; t0 < (z + 1) * KVSPAN; t0 += 64) {
        __syncthreads();
        const _Float16* Kg = Kh + ((long)h * SEQLEN + t0) * HDP;
        for (int i = tid; i < 768; i += 512) {       // 64 rows x 12 chunks
            const int r = i / 12, c = (i - r * 12) * 8;
            *(half8*)&Ks[r * KSTRIDE + c] = *(const half8*)&Kg[(long)r * HDP + c];
        }
        const _Float16* Vtg = Vt + (long)h * HD * SEQLEN + t0;
        for (int i = tid; i < 640; i += 512) {       // 80 d-rows x 8 chunks
            const int d = i >> 3, c = (i & 7) * 8;
            const half8 v = *(const half8*)&Vtg[(long)d * SEQLEN + c];
            const int nt = d >> 4, ld = d & 15;
            const int ct = c >> 4, qb = (c & 15) >> 2;   // qb in {0, 2}
            *(half4*)&VF[(nt * 64 + qb * 16 + ld) * VFSTRIDE + ct * 4]       = lo4(v);
            *(half4*)&VF[(nt * 64 + (qb + 1) * 16 + ld) * VFSTRIDE + ct * 4] = hi4(v);
        }
        __syncthreads();

        // S^T: 4 col-tiles of 16 keys each (operands swapped: A=K, B=Q)
        f32x4 sa[4] = {};
#pragma unroll
        for (int kk = 0; kk < 3; kk++)
#pragma unroll
            for (int ct = 0; ct < 4; ct++) {
                half8 kf = *(const half8*)&Ks[(ct * 16 + l15) * KSTRIDE + kk * 32 + quad * 8];
                sa[ct] = mfma_16x16x32(kf, qf[kk], sa[ct]);
            }

        // P^T = exp2(S^T) straight into 16x16x16 B-operand registers
        half4 pb[4];
#pragma unroll
        for (int ct = 0; ct < 4; ct++)
#pragma unroll
            for (int r = 0; r < 4; r++) {
                const float p = EXP2F(sa[ct][r]);
                l_acc += p;
                pb[ct][r] = (_Float16)p;
            }

        // O^T += V^T * P^T : 2 lane-contiguous half8 reads per nt
#pragma unroll
        for (int nt = 0; nt < 5; nt++) {
            const half8 va = *(const half8*)&VF[(nt * 64 + lane) * VFSTRIDE];
            const half8 vb = *(const half8*)&VF[(nt * 64 + lane) * VFSTRIDE + 8];
            oaccT[nt] = mfma_16x16x16(lo4(va), pb[0], oaccT[nt]);
            oaccT[nt] = mfma_16x16x16(hi4(va), pb[1], oaccT[nt]);
            oaccT[nt] = mfma_16x16x16(lo4(vb), pb[2], oaccT[nt]);
            oaccT[nt] = mfma_16x16x16(hi4(vb), pb[3], oaccT[nt]);
        }
    }

    // l: sum the 4 quads holding this query's key-chunks
    l_acc += __shfl_xor(l_acc, 16);
    l_acc += __shfl_xor(l_acc, 32);
    const float inv = 1.0f / l_acc;

    // partials: z 0,1 -> Ohat0 region, z 2,3 -> Ohat1 region
    _Float16* Oz = (z < 2) ? Ohat0 : Ohat1;
    const long obase = ((long)(z & 1) * NHEADS + h) * SEQLEN;
    const long lbase = ((long)z * NHEADS + h) * SEQLEN;
    const long row = s0 + wave * 16 + l15;           // this lane's query
#pragma unroll
    for (int nt = 0; nt < 5; nt++) {
        half4 o;
#pragma unroll
        for (int r = 0; r < 4; r++) o[r] = (_Float16)(oaccT[nt][r] * inv);
        *(half4*)&Oz[(obase + row) * HD + nt * 16 + quad * 4] = o;
    }
    if (quad == 0)
        Lpart[lbase + row] = l_acc;
}

// ---------------------------------------------------------------------------
// out = sum_z Ohat_z * l_z / sum_z l_z  -> attnb f16 [s][h*80+d]
__global__ __launch_bounds__(256)
void attn_combine(const _Float16* __restrict__ Ohat0,
                  const _Float16* __restrict__ Ohat1,
                  const float* __restrict__ Lp,
                  _Float16* __restrict__ attnb) {
    const int i = blockIdx.x * 256 + threadIdx.x;
    if (i >= SEQLEN * DIMM / 4) return;
    const int flat = i * 4;
    const int s = flat / DIMM;
    const int rem = flat - s * DIMM;
    const int h = rem / HD;
    const int d = rem - h * HD;
    float l[NSPLIT], lsum = 0.f;
#pragma unroll
    for (int zi = 0; zi < NSPLIT; zi++) {
        l[zi] = Lp[((long)zi * NHEADS + h) * SEQLEN + s];
        lsum += l[zi];
    }
    const float invl = 1.0f / lsum;
    float acc[4] = {0.f, 0.f, 0.f, 0.f};
#pragma unroll
    for (int zi = 0; zi < NSPLIT; zi++) {
        const _Float16* Oz = (zi < 2) ? Ohat0 : Ohat1;
        const long obase = ((long)(zi & 1) * NHEADS + h) * SEQLEN;
        const half4 o = *(const half4*)&Oz[(obase + s) * HD + d];
        const float w = l[zi] * invl;
#pragma unroll
        for (int j = 0; j < 4; j++) acc[j] += (float)o[j] * w;
    }
    half4 o;
#pragma unroll
    for (int j = 0; j < 4; j++) o[j] = (_Float16)acc[j];
    *(half4*)&attnb[(long)s * DIMM + rem] = o;
}

// ---------------------------------------------------------------------------
extern "C" void kernel_launch(void* const* d_in, const int* in_sizes, int n_in,
                              void* d_out, int out_size, void* d_ws, size_t ws_size,
                              hipStream_t stream) {
    const float* hs     = (const float*)d_in[0];
    // d_in[1] = cu_seqlens [0, 2048] — reference does no masking; unused.
    const float* cosb   = (const float*)d_in[2];
    const float* sinb   = (const float*)d_in[3];
    const float* w_qkv  = (const float*)d_in[4];
    const float* b_qkv  = (const float*)d_in[5];
    const float* w_proj = (const float*)d_in[6];
    const float* b_proj = (const float*)d_in[7];
    float* out = (float*)d_out;

    _Float16* hsb    = (_Float16*)d_ws;                       // 2048*1280
    _Float16* wqkvb  = hsb    + (long)SEQLEN * DIMM;          // 3840*1280
    _Float16* wprojb = wqkvb  + (long)QKV_N * DIMM;           // 1280*1280
    _Float16* qkv    = wprojb + (long)DIMM * DIMM;            // 2048*3840
    _Float16* Qh     = qkv    + (long)SEQLEN * QKV_N;         // 16*2048*96
    _Float16* Kh     = Qh     + (long)NHEADS * SEQLEN * HDP;
    _Float16* Vtb    = Kh     + (long)NHEADS * SEQLEN * HDP;  // 16*80*2048
    _Float16* attnb  = Vtb    + (long)NHEADS * HD * SEQLEN;   // 2048*1280

    // attention partials alias DEAD regions during attention:
    //   Ohat0 (z=0,1): hsb+wqkvb region (15.07 MB) — dead after QKV GEMM.
    //   Ohat1 (z=2,3): qkv region (15.73 MB) — dead after rope_repack_t.
    _Float16* Ohat0  = (_Float16*)d_ws;
    float*    LpartB = (float*)(Ohat0 + (long)2 * NHEADS * SEQLEN * HD);
    _Float16* Ohat1  = qkv;

    {
        const int ntot = (SEQLEN * DIMM + QKV_N * DIMM + DIMM * DIMM) / 4;
        cast_all<<<(ntot + 255) / 256, 256, 0, stream>>>(
            hs, w_qkv, w_proj, hsb, wqkvb, wprojb);
    }

    gemm_bt64<true><<<dim3(SEQLEN / 64, QKV_N / 128), 256, 0, stream>>>(
        hsb, wqkvb, b_qkv, qkv, SEQLEN, QKV_N, DIMM);

    rope_repack_t<<<dim3(SEQLEN / 64, NHEADS), 256, 0, stream>>>(
        qkv, cosb, sinb, Qh, Kh, Vtb);

    attn_kernel<<<dim3(SEQLEN / 128, NHEADS, NSPLIT), 512, 0, stream>>>(
        Qh, Kh, Vtb, Ohat0, Ohat1, LpartB);

    attn_combine<<<(SEQLEN * DIMM / 4 + 255) / 256, 256, 0, stream>>>(
        Ohat0, Ohat1, LpartB, attnb);

    gemm_bt64<false><<<dim3(SEQLEN / 64, DIMM / 128), 256, 0, stream>>>(
        attnb, wprojb, b_proj, out, SEQLEN, DIMM, DIMM);
}